// Round 6
// baseline (11217.575 us; speedup 1.0000x reference)
//
#include <hip/hip_runtime.h>
#include <math.h>

// Problem constants (fixed by the reference)
constexpr int N_ = 101, H_ = 128;
constexpr float EPS_ = 1e-5f;

// LDS layout (float words) — 3128 words = 12.5 KB (two batches per block)
constexpr int OFF_BUF0 = 0;                   // 812: attn / y-partials batch0
constexpr int OFF_BUF1 = OFF_BUF0 + 812;      // 812: batch1
constexpr int OFF_RED0 = OFF_BUF1 + 812;      // 512: partials batch0
constexpr int OFF_RED1 = OFF_RED0 + 512;      // 512: batch1
constexpr int OFF_MB0  = OFF_RED1 + 512;      // 104: mask batch0
constexpr int OFF_MB1  = OFF_MB0 + 104;       // 104: mask batch1
constexpr int OFF_DV0  = OFF_MB1 + 104;       // 128: d / xn batch0
constexpr int OFF_DV1  = OFF_DV0 + 128;       // 128: batch1
constexpr int OFF_SC   = OFF_DV1 + 128;       // [0]=idx0 [1]=idx1
constexpr int LDS_WORDS = OFF_SC + 8;

__global__ __launch_bounds__(512, 2) void gat_decoder(
    const float* __restrict__ enc, const float* __restrict__ pool,
    const float* __restrict__ capac, const float* __restrict__ dem,
    const float* __restrict__ fcw, const float* __restrict__ fc1w,
    const float* __restrict__ lng, const float* __restrict__ lnb,
    const float* __restrict__ wq, const float* __restrict__ wk,
    const float* __restrict__ wvm, const float* __restrict__ wo,
    const float* __restrict__ kpw, const float* __restrict__ plg,
    const float* __restrict__ plb, const int* __restrict__ tp,
    float* __restrict__ out, int Bv, int ns)
{
  __shared__ float sm[LDS_WORDS];
  const int tid  = threadIdx.x;
  const int lane = tid & 63;
  const int wvid = tid >> 6;        // wave id 0..7 (= head id in DE phase)
  const int j    = tid & 127;       // output column
  const int s    = tid >> 7;        // k-slice 0..3
  const int w1   = wvid & 1;        // j-half of this wave
  const int b0   = blockIdx.x * 2;
  const int b1   = b0 + 1;

  const float NEG_INF = -__builtin_inff();
  int ti = tp[0];
  float Tf = (ti > 1000000 || ti < -1000000) ? __int_as_float((int)ti) : (float)ti;
  const float inv_sqrt_h = 1.0f / sqrtf(128.0f);
  const float PSUM_CONST = 1.0f + (float)N_ * 1e-10f;

  const float* enc0 = enc + (size_t)b0 * (N_ * H_);
  const float* enc1 = enc + (size_t)b1 * (N_ * H_);

  float* BUF0 = sm + OFF_BUF0; float* BUF1 = sm + OFF_BUF1;
  float* RED0 = sm + OFF_RED0; float* RED1 = sm + OFF_RED1;
  float* MB0  = sm + OFF_MB0;  float* MB1  = sm + OFF_MB1;
  float* DV0  = sm + OFF_DV0;  float* DV1  = sm + OFF_DV1;
  int*   SCI  = ((int*)sm) + OFF_SC;

  const int g  = __builtin_amdgcn_readfirstlane(s);
  const int r0 = g * 26;
  const int nr = (g == 3) ? 23 : 26;

  // ---------- Kp, V in (s,j)-layout registers, per batch ----------
  float kp0_r[26], vh0_r[26], kp1_r[26], vh1_r[26];
  {
    #pragma unroll
    for (int t = 0; t < 26; ++t) { kp0_r[t]=0.f; vh0_r[t]=0.f; kp1_r[t]=0.f; vh1_r[t]=0.f; }
    for (int k0 = 0; k0 < H_; k0 += 8) {
      float wp8[8], wv8[8];
      #pragma unroll
      for (int kk = 0; kk < 8; ++kk) { wp8[kk] = kpw[(k0+kk)*H_ + j]; wv8[kk] = wvm[(k0+kk)*H_ + j]; }
      #pragma unroll
      for (int t = 0; t < 26; ++t) if (t < nr) {
        const float* ea = enc0 + (r0 + t) * H_ + k0;   // wave-uniform
        const float* eb = enc1 + (r0 + t) * H_ + k0;
        #pragma unroll
        for (int kk = 0; kk < 8; ++kk) {
          kp0_r[t] = fmaf(ea[kk], wp8[kk], kp0_r[t]);
          vh0_r[t] = fmaf(ea[kk], wv8[kk], vh0_r[t]);
          kp1_r[t] = fmaf(eb[kk], wp8[kk], kp1_r[t]);
          vh1_r[t] = fmaf(eb[kk], wv8[kk], vh1_r[t]);
        }
      }
    }
  }

  // ---------- K in wave-layout registers: wave h, lane l holds K[l][h*16+d], K[l+64][h*16+d] ----------
  float kh0A[16], kh0B[16], kh1A[16], kh1B[16];
  {
    #pragma unroll
    for (int d = 0; d < 16; ++d) { kh0A[d]=0.f; kh0B[d]=0.f; kh1A[d]=0.f; kh1B[d]=0.f; }
    const int row2 = (lane + 64 < N_) ? (lane + 64) : lane;   // safe dummy
    const float* e0a = enc0 + (size_t)lane * H_;
    const float* e0b = enc0 + (size_t)row2 * H_;
    const float* e1a = enc1 + (size_t)lane * H_;
    const float* e1b = enc1 + (size_t)row2 * H_;
    for (int k = 0; k < H_; ++k) {
      const float* wr = wk + k * H_ + wvid * 16;   // wave-uniform
      const float ea0 = e0a[k], eb0 = e0b[k], ea1 = e1a[k], eb1 = e1b[k];
      #pragma unroll
      for (int d = 0; d < 16; ++d) {
        const float w = wr[d];
        kh0A[d] = fmaf(ea0, w, kh0A[d]);
        kh0B[d] = fmaf(eb0, w, kh0B[d]);
        kh1A[d] = fmaf(ea1, w, kh1A[d]);
        kh1B[d] = fmaf(eb1, w, kh1B[d]);
      }
    }
  }

  // ---------- wq in per-wave q-layout: row (l>>4)*32+r, col h*16+(l&15) ----------
  float wq2[32];
  {
    const int colq = wvid * 16 + (lane & 15);
    const int rowb = (lane >> 4) * 32;
    #pragma unroll
    for (int r = 0; r < 32; ++r) wq2[r] = wq[(rowb + r) * H_ + colq];
  }

  // ---------- pool_proc partials for both batches ----------
  {
    const float* pb0 = pool + (size_t)b0 * H_;
    const float* pb1 = pool + (size_t)b1 * H_;
    float p0 = 0.f, p1 = 0.f;
    #pragma unroll
    for (int r = 0; r < 32; ++r) {
      const float w = fc1w[(s * 32 + r) * H_ + j];
      p0 = fmaf(pb0[s * 32 + r], w, p0);
      p1 = fmaf(pb1[s * 32 + r], w, p1);
    }
    RED0[s * H_ + j] = p0;
    RED1[s * H_ + j] = p1;
  }
  if (tid == 0) { SCI[0] = 0; SCI[1] = 0; }
  __syncthreads();

  // ---------- waves 0/1 hold per-batch decode state in registers ----------
  float capv=0.f, cap=0.f, lpsum=0.f, demA=0.f, demC=0.f, ppA=0.f, ppC=0.f;
  float lngA=0.f,lngC=0.f,lnbA=0.f,lnbC=0.f,plgA=0.f,plgC=0.f,plbA=0.f,plbC=0.f;
  float fcapA=0.f, fcapC=0.f;
  int vis = 0; bool m1a=false, m1c=false;
  if (wvid < 2) {
    const int bb = b0 + wvid;
    const float* REDb = (wvid == 0) ? RED0 : RED1;
    float* MBb = (wvid == 0) ? MB0 : MB1;
    capv = capac[bb]; cap = capv;
    demA = dem[(size_t)bb * N_ + lane];
    demC = (lane + 64 < N_) ? dem[(size_t)bb * N_ + lane + 64] : 0.f;
    ppA = REDb[lane] + REDb[128+lane] + REDb[256+lane] + REDb[384+lane];
    ppC = REDb[64+lane] + REDb[192+lane] + REDb[320+lane] + REDb[448+lane];
    lngA = lng[lane]; lngC = lng[lane+64];
    lnbA = lnb[lane]; lnbC = lnb[lane+64];
    plgA = plg[lane]; plgC = plg[lane+64];
    plbA = plb[lane]; plbC = plb[lane+64];
    fcapA = fcw[128*H_ + lane]; fcapC = fcw[128*H_ + 64 + lane];
    // initial masks (i=0, idx=0, mask1=0)
    bool infA = (lane >= 1) && (demA > cap);
    bool infB = (lane + 64 >= N_) || (demC > cap);
    bool feasA = (lane >= 1) && !infA;
    bool feasB = (lane + 64 < N_) && !infB;
    const bool anyf = __any(feasA || feasB);
    MBb[lane] = (lane == 0) ? (anyf ? 1.f : 0.f) : (infA ? 1.f : 0.f);
    if (lane + 64 < N_) MBb[lane + 64] = infB ? 1.f : 0.f;
  }
  __syncthreads();

  // ---------- decode loop: 8 barriers/step, 2 batches/phase ----------
  for (int i = 0; i < ns; ++i) {
    const int pidx0 = __builtin_amdgcn_readfirstlane(SCI[0]);
    const int pidx1 = __builtin_amdgcn_readfirstlane(SCI[1]);

    // B: d-partials = inp @ fc_w (fc streamed from L2 in 2 chunks of 16)
    {
      const float* ep0 = enc0 + (size_t)pidx0 * H_ + s * 32;
      const float* ep1 = enc1 + (size_t)pidx1 * H_ + s * 32;
      float p0 = 0.f, p1 = 0.f;
      #pragma unroll
      for (int half = 0; half < 2; ++half) {
        float fcv[16];
        #pragma unroll
        for (int r = 0; r < 16; ++r) fcv[r] = fcw[(s*32 + half*16 + r) * H_ + j];
        #pragma unroll
        for (int r = 0; r < 16; ++r) {
          p0 = fmaf(fcv[r], ep0[half*16 + r], p0);
          p1 = fmaf(fcv[r], ep1[half*16 + r], p1);
        }
      }
      RED0[s*H_ + j] = p0; RED1[s*H_ + j] = p1;
    }
    __syncthreads();                                            // S1

    // B-LN (wave 0 -> batch0, wave 1 -> batch1)
    if (wvid < 2) {
      const float* REDb = (wvid == 0) ? RED0 : RED1;
      float* DVb = (wvid == 0) ? DV0 : DV1;
      float a = REDb[lane]+REDb[128+lane]+REDb[256+lane]+REDb[384+lane] + cap*fcapA + ppA;
      float c = REDb[64+lane]+REDb[192+lane]+REDb[320+lane]+REDb[448+lane] + cap*fcapC + ppC;
      float ssum = a + c;
      #pragma unroll
      for (int o = 32; o; o >>= 1) ssum += __shfl_xor(ssum, o, 64);
      const float mu = ssum * (1.f/128.f);
      const float da = a - mu, dc = c - mu;
      float vvv = da*da + dc*dc;
      #pragma unroll
      for (int o = 32; o; o >>= 1) vvv += __shfl_xor(vvv, o, 64);
      const float inv = 1.0f / sqrtf(vvv * (1.f/128.f) + EPS_);
      DVb[lane]    = da * inv * lngA + lnbA;
      DVb[lane+64] = dc * inv * lngC + lnbC;
    }
    __syncthreads();                                            // S2

    // DE (wave = head): in-wave q, logits from kh registers, softmax, attn
    {
      const int kbase = (lane >> 4) * 32;
      float q0 = 0.f, q1 = 0.f;
      #pragma unroll
      for (int r = 0; r < 32; ++r) {
        q0 = fmaf(wq2[r], DV0[kbase + r], q0);
        q1 = fmaf(wq2[r], DV1[kbase + r], q1);
      }
      q0 += __shfl_xor(q0, 16, 64); q0 += __shfl_xor(q0, 32, 64);
      q1 += __shfl_xor(q1, 16, 64); q1 += __shfl_xor(q1, 32, 64);
      const int n1 = lane, n2 = lane + 64;
      // batch 0
      {
        float qd[16];
        #pragma unroll
        for (int d = 0; d < 16; ++d) qd[d] = __shfl(q0, d, 64);
        float a1 = 0.f, a2 = 0.f;
        #pragma unroll
        for (int d = 0; d < 16; ++d) { a1 = fmaf(qd[d], kh0A[d], a1); a2 = fmaf(qd[d], kh0B[d], a2); }
        a1 = (MB0[n1] > 0.f) ? NEG_INF : a1 * 0.25f;
        a2 = (n2 < N_) ? ((MB0[n2] > 0.f) ? NEG_INF : a2 * 0.25f) : NEG_INF;
        float mx = fmaxf(a1, a2);
        #pragma unroll
        for (int o = 32; o; o >>= 1) mx = fmaxf(mx, __shfl_xor(mx, o, 64));
        float e1 = expf(a1 - mx);
        float e2 = (n2 < N_) ? expf(a2 - mx) : 0.f;
        float ssum = e1 + e2;
        #pragma unroll
        for (int o = 32; o; o >>= 1) ssum += __shfl_xor(ssum, o, 64);
        BUF0[wvid * N_ + n1] = e1 / ssum;
        if (n2 < N_) BUF0[wvid * N_ + n2] = e2 / ssum;
      }
      // batch 1
      {
        float qd[16];
        #pragma unroll
        for (int d = 0; d < 16; ++d) qd[d] = __shfl(q1, d, 64);
        float a1 = 0.f, a2 = 0.f;
        #pragma unroll
        for (int d = 0; d < 16; ++d) { a1 = fmaf(qd[d], kh1A[d], a1); a2 = fmaf(qd[d], kh1B[d], a2); }
        a1 = (MB1[n1] > 0.f) ? NEG_INF : a1 * 0.25f;
        a2 = (n2 < N_) ? ((MB1[n2] > 0.f) ? NEG_INF : a2 * 0.25f) : NEG_INF;
        float mx = fmaxf(a1, a2);
        #pragma unroll
        for (int o = 32; o; o >>= 1) mx = fmaxf(mx, __shfl_xor(mx, o, 64));
        float e1 = expf(a1 - mx);
        float e2 = (n2 < N_) ? expf(a2 - mx) : 0.f;
        float ssum = e1 + e2;
        #pragma unroll
        for (int o = 32; o; o >>= 1) ssum += __shfl_xor(ssum, o, 64);
        BUF1[wvid * N_ + n1] = e1 / ssum;
        if (n2 < N_) BUF1[wvid * N_ + n2] = e2 / ssum;
      }
    }
    __syncthreads();                                            // S3

    // F1: x-partials = attn @ V (V in registers)
    {
      const float* aw0 = BUF0 + (j >> 4) * N_ + r0;
      const float* aw1 = BUF1 + (j >> 4) * N_ + r0;
      float x0 = 0.f, x1 = 0.f;
      #pragma unroll
      for (int t = 0; t < 26; ++t) if (t < nr) {
        x0 = fmaf(aw0[t], vh0_r[t], x0);
        x1 = fmaf(aw1[t], vh1_r[t], x1);
      }
      RED0[s*H_ + j] = x0; RED1[s*H_ + j] = x1;
    }
    __syncthreads();                                            // S4

    // F3: y-partials = x @ wo (x 4-slice-summed inline via float4; wo streamed)
    {
      float y0 = 0.f, y1 = 0.f;
      #pragma unroll
      for (int r4 = 0; r4 < 8; ++r4) {
        const int k = s * 32 + r4 * 4;
        float wov[4];
        #pragma unroll
        for (int rr = 0; rr < 4; ++rr) wov[rr] = wo[(k + rr) * H_ + j];
        float4 u0 = *(const float4*)&RED0[k];
        float4 u1 = *(const float4*)&RED0[128 + k];
        float4 u2 = *(const float4*)&RED0[256 + k];
        float4 u3 = *(const float4*)&RED0[384 + k];
        y0 = fmaf(wov[0], ((u0.x + u1.x) + u2.x) + u3.x, y0);
        y0 = fmaf(wov[1], ((u0.y + u1.y) + u2.y) + u3.y, y0);
        y0 = fmaf(wov[2], ((u0.z + u1.z) + u2.z) + u3.z, y0);
        y0 = fmaf(wov[3], ((u0.w + u1.w) + u2.w) + u3.w, y0);
        float4 t0 = *(const float4*)&RED1[k];
        float4 t1 = *(const float4*)&RED1[128 + k];
        float4 t2 = *(const float4*)&RED1[256 + k];
        float4 t3 = *(const float4*)&RED1[384 + k];
        y1 = fmaf(wov[0], ((t0.x + t1.x) + t2.x) + t3.x, y1);
        y1 = fmaf(wov[1], ((t0.y + t1.y) + t2.y) + t3.y, y1);
        y1 = fmaf(wov[2], ((t0.z + t1.z) + t2.z) + t3.z, y1);
        y1 = fmaf(wov[3], ((t0.w + t1.w) + t2.w) + t3.w, y1);
      }
      BUF0[s*H_ + j] = y0; BUF1[s*H_ + j] = y1;
    }
    __syncthreads();                                            // S5

    // F4-LN (waves 0/1): sum + LayerNorm(ptr) -> DV (= xn)
    if (wvid < 2) {
      const float* BUFb = (wvid == 0) ? BUF0 : BUF1;
      float* DVb = (wvid == 0) ? DV0 : DV1;
      float a = BUFb[lane]+BUFb[128+lane]+BUFb[256+lane]+BUFb[384+lane];
      float c = BUFb[64+lane]+BUFb[192+lane]+BUFb[320+lane]+BUFb[448+lane];
      float ssum = a + c;
      #pragma unroll
      for (int o = 32; o; o >>= 1) ssum += __shfl_xor(ssum, o, 64);
      const float mu = ssum * (1.f/128.f);
      const float da = a - mu, dc = c - mu;
      float vvv = da*da + dc*dc;
      #pragma unroll
      for (int o = 32; o; o >>= 1) vvv += __shfl_xor(vvv, o, 64);
      const float inv = 1.0f / sqrtf(vvv * (1.f/128.f) + EPS_);
      DVb[lane]    = da * inv * plgA + plbA;
      DVb[lane+64] = dc * inv * plgC + plbC;
    }
    __syncthreads();                                            // S6

    // G1: comp halves via register Kp + 64-lane butterflies (both batches)
    {
      const float d0j = DV0[j], d1j = DV1[j];
      #pragma unroll
      for (int t = 0; t < 26; ++t) if (t < nr) {
        float v0 = d0j * kp0_r[t];
        float v1 = d1j * kp1_r[t];
        #pragma unroll
        for (int o = 32; o; o >>= 1) { v0 += __shfl_xor(v0, o, 64); v1 += __shfl_xor(v1, o, 64); }
        if (lane == 0) { RED0[w1*256 + r0 + t] = v0; RED1[w1*256 + r0 + t] = v1; }
      }
    }
    __syncthreads();                                            // S7

    // G2 (wave 0 -> batch0, wave 1 -> batch1): argmax, lp, state, next masks
    if (wvid < 2) {
      const float* REDb = (wvid == 0) ? RED0 : RED1;
      float* MBb = (wvid == 0) ? MB0 : MB1;
      const int bb = b0 + wvid;
      const int n1 = lane, n2 = lane + 64;
      const bool mbA = (MBb[n1] > 0.f);
      const bool mbB = (n2 >= N_) || (MBb[n2] > 0.f);
      const bool allmb = __all(mbA && mbB);
      float c1 = mbA ? NEG_INF : (REDb[n1] + REDb[256+n1]) * inv_sqrt_h / Tf;
      float c2 = (n2 < N_ && !mbB) ? (REDb[n2] + REDb[256+n2]) * inv_sqrt_h / Tf : NEG_INF;
      if (allmb) { c1 = 0.f; c2 = (n2 < N_) ? 0.f : NEG_INF; }
      float bv = c1; int bi = n1;
      if (c2 > bv) { bv = c2; bi = n2; }
      #pragma unroll
      for (int o = 32; o; o >>= 1) {
        float ov = __shfl_xor(bv, o, 64);
        int   oi = __shfl_xor(bi, o, 64);
        if (ov > bv || (ov == bv && oi < bi)) { bv = ov; bi = oi; }
      }
      float e1 = expf(c1 - bv);
      float e2 = (n2 < N_) ? expf(c2 - bv) : 0.f;
      float ssum = e1 + e2;
      #pragma unroll
      for (int o = 32; o; o >>= 1) ssum += __shfl_xor(ssum, o, 64);
      float lp = logf((1.0f / ssum + 1e-10f) / PSUM_CONST);
      if (vis >= N_ - 1) lp = 0.f;
      lpsum += lp;
      const float dsel = (bi < 64) ? __shfl(demA, bi, 64) : __shfl(demC, bi - 64, 64);
      cap = (bi == 0) ? capv : (cap - dsel);
      if (bi != 0) {
        const bool newly = ((bi == n1) && !m1a) || ((bi == n2) && !m1c);
        if (__any(newly)) vis += 1;
        m1a = m1a || (bi == n1);
        m1c = m1c || (bi == n2);
      }
      bool infA = (n1 >= 1) && (m1a || demA > cap);
      bool infB = (n2 >= N_) || m1c || (demC > cap);
      bool feasA = (n1 >= 1) && !infA;
      bool feasB = (n2 < N_) && !infB;
      const bool anyf = __any(feasA || feasB);
      const bool depot_m = anyf && (bi == 0);
      MBb[n1] = (n1 == 0) ? (depot_m ? 1.f : 0.f) : (infA ? 1.f : 0.f);
      if (n2 < N_) MBb[n2] = infB ? 1.f : 0.f;
      if (lane == 0) {
        SCI[wvid] = bi;
        out[(size_t)bb * (ns + 2) + 1 + i] = (float)bi;
      }
    }
    __syncthreads();                                            // S8
  }

  if (wvid < 2 && lane == 0) {
    const int bb = b0 + wvid;
    const int last = SCI[wvid];
    out[(size_t)bb * (ns + 2)] = 0.f;
    out[(size_t)bb * (ns + 2) + ns + 1] = (last == 0) ? -1.f : 0.f;
    out[(size_t)Bv * (ns + 2) + bb] = lpsum;   // log_p
  }
}

extern "C" void kernel_launch(void* const* d_in, const int* in_sizes, int n_in,
                              void* d_out, int out_size, void* d_ws, size_t ws_size,
                              hipStream_t stream) {
  const int Bv = in_sizes[0] / (N_ * H_);   // 1024
  const int ns = out_size / Bv - 3;         // B*(ns+2) actions + B log_p => 120
  gat_decoder<<<dim3(Bv / 2), dim3(512), 0, stream>>>(
      (const float*)d_in[0],  (const float*)d_in[1],  (const float*)d_in[2],
      (const float*)d_in[3],  (const float*)d_in[4],  (const float*)d_in[5],
      (const float*)d_in[6],  (const float*)d_in[7],  (const float*)d_in[8],
      (const float*)d_in[9],  (const float*)d_in[10], (const float*)d_in[11],
      (const float*)d_in[12], (const float*)d_in[13], (const float*)d_in[14],
      (const int*)d_in[16],
      (float*)d_out, Bv, ns);
}

// Round 7
// 6224.607 us; speedup vs baseline: 1.8021x; 1.8021x over previous
//
#include <hip/hip_runtime.h>
#include <math.h>

// Problem constants (fixed by the reference)
constexpr int N_ = 101, H_ = 128, NH_ = 8, HD_ = 16;
constexpr int SK = 129;              // padded LDS stride for Kh (bank-conflict-free)
constexpr float EPS_ = 1e-5f;

// LDS layout (float words) — 14,872 words = 59,488 B (< 64 KiB)
constexpr int OFF_KH  = 0;                    // 101 rows * stride 129 (padded to 13032)
constexpr int OFF_BUF = 13032;                // 816: attn weights / y-partials
constexpr int OFF_RED = OFF_BUF + 816;        // 512: d-partials / x-partials (16B aligned)
constexpr int OFF_CMP = OFF_RED + 512;        // 512: comp halves
constexpr int LDS_WORDS = OFF_CMP + 512;

__global__ __launch_bounds__(512, 2) void gat_decoder(
    const float* __restrict__ enc, const float* __restrict__ pool,
    const float* __restrict__ capac, const float* __restrict__ dem,
    const float* __restrict__ fcw, const float* __restrict__ fc1w,
    const float* __restrict__ lng, const float* __restrict__ lnb,
    const float* __restrict__ wq, const float* __restrict__ wk,
    const float* __restrict__ wvm, const float* __restrict__ wo,
    const float* __restrict__ kpw, const float* __restrict__ plg,
    const float* __restrict__ plb, const int* __restrict__ tp,
    float* __restrict__ out, int Bv, int ns)
{
  __shared__ float sm[LDS_WORDS];
  const int tid  = threadIdx.x;
  const int b    = blockIdx.x;
  const int lane = tid & 63;
  const int wvid = tid >> 6;        // wave id 0..7 (= head id in DE phase)
  const int j    = tid & 127;       // output column
  const int s    = tid >> 7;        // k-slice 0..3
  const int w1   = wvid & 1;        // j-half of this wave

  const float NEG_INF = -__builtin_inff();
  int ti = tp[0];
  float Tf = (ti > 1000000 || ti < -1000000) ? __int_as_float((int)ti) : (float)ti;
  const float inv_sqrt_h = 1.0f / sqrtf(128.0f);
  const float PSUM_CONST = 1.0f + (float)N_ * 1e-10f;

  const float* encb = enc + (size_t)b * (N_ * H_);

  float* KH  = sm + OFF_KH;
  float* BUF = sm + OFF_BUF;
  float* RED = sm + OFF_RED;
  float* CMP = sm + OFF_CMP;

  const int g  = __builtin_amdgcn_readfirstlane(s);  // wave-uniform row group
  const int r0 = g * 26;
  const int nr = (g == 3) ? 23 : 26;

  // ---------- precompute Kh into LDS ----------
  {
    float acc[26];
    #pragma unroll
    for (int t = 0; t < 26; ++t) acc[t] = 0.f;
    for (int k0 = 0; k0 < H_; k0 += 8) {
      float w8[8];
      #pragma unroll
      for (int kk = 0; kk < 8; ++kk) w8[kk] = wk[(k0 + kk) * H_ + j];
      #pragma unroll
      for (int t = 0; t < 26; ++t) {
        if (t < nr) {
          const float* ep = encb + (r0 + t) * H_ + k0;   // wave-uniform address
          #pragma unroll
          for (int kk = 0; kk < 8; ++kk) acc[t] = fmaf(ep[kk], w8[kk], acc[t]);
        }
      }
    }
    #pragma unroll
    for (int t = 0; t < 26; ++t)
      if (t < nr) KH[(r0 + t) * SK + j] = acc[t];
  }

  // ---------- Kp, Vh in registers: column slice [row r0+t][j] ----------
  float kp_r[26], vh_r[26];
  {
    #pragma unroll
    for (int t = 0; t < 26; ++t) { kp_r[t] = 0.f; vh_r[t] = 0.f; }
    for (int k0 = 0; k0 < H_; k0 += 8) {
      float wp8[8], wv8[8];
      #pragma unroll
      for (int kk = 0; kk < 8; ++kk) {
        wp8[kk] = kpw[(k0 + kk) * H_ + j];
        wv8[kk] = wvm[(k0 + kk) * H_ + j];
      }
      #pragma unroll
      for (int t = 0; t < 26; ++t) {
        if (t < nr) {
          const float* ep = encb + (r0 + t) * H_ + k0;
          #pragma unroll
          for (int kk = 0; kk < 8; ++kk) {
            kp_r[t] = fmaf(ep[kk], wp8[kk], kp_r[t]);
            vh_r[t] = fmaf(ep[kk], wv8[kk], vh_r[t]);
          }
        }
      }
    }
  }

  // ---------- weights in registers ----------
  float fc_r[32], wo_r[32], wq2[32];
  #pragma unroll
  for (int r = 0; r < 32; ++r) {
    fc_r[r] = fcw[(s * 32 + r) * H_ + j];
    wo_r[r] = wo[(s * 32 + r) * H_ + j];
  }
  {
    const int colq = wvid * 16 + (lane & 15);
    const int rowb = (lane >> 4) * 32;
    #pragma unroll
    for (int r = 0; r < 32; ++r) wq2[r] = wq[(rowb + r) * H_ + colq];
  }

  // pool_proc partials
  {
    const float* pb = pool + (size_t)b * H_;
    float p = 0.f;
    #pragma unroll
    for (int r = 0; r < 32; ++r) p = fmaf(pb[s * 32 + r], fc1w[(s * 32 + r) * H_ + j], p);
    RED[s * H_ + j] = p;
  }
  __syncthreads();

  // ---------- per-wave redundant decode state (registers, identical across waves) ----------
  const int n1 = lane, n2 = lane + 64;
  float ppA = RED[lane] + RED[128 + lane] + RED[256 + lane] + RED[384 + lane];
  float ppC = RED[64 + lane] + RED[192 + lane] + RED[320 + lane] + RED[448 + lane];
  float capv = capac[b], cap = capv, lpsum = 0.f;
  float demA = dem[(size_t)b * N_ + lane];
  float demC = (n2 < N_) ? dem[(size_t)b * N_ + n2] : 0.f;
  float lngA = lng[lane], lngC = lng[lane + 64];
  float lnbA = lnb[lane], lnbC = lnb[lane + 64];
  float plgA = plg[lane], plgC = plg[lane + 64];
  float plbA = plb[lane], plbC = plb[lane + 64];
  float fcapA = fcw[128 * H_ + lane], fcapC = fcw[128 * H_ + 64 + lane];
  int vis = 0, pidx = 0;
  bool m1a = false, m1c = false, mbA, mbB;
  {
    // initial masks (i=0, idx=0, mask1=0): depot masked iff any feasible customer
    bool infA = (n1 >= 1) && (demA > cap);
    bool infB = (n2 >= N_) || (demC > cap);
    bool feasA = (n1 >= 1) && !infA;
    bool feasB = (n2 < N_) && !infB;
    const bool anyf = __any(feasA || feasB);
    mbA = (n1 == 0) ? anyf : infA;
    mbB = infB;
  }
  __syncthreads();

  // ---------- decode loop: 5 barriers/step, no single-wave serial phases ----------
  for (int i = 0; i < ns; ++i) {
    const int pu = __builtin_amdgcn_readfirstlane(pidx);

    // B: d-partials = inp @ fc_w (enc row read wave-uniform -> scalar loads)
    {
      const float* ep = encb + (size_t)pu * H_ + s * 32;
      float part = 0.f;
      #pragma unroll
      for (int r = 0; r < 32; ++r) part = fmaf(fc_r[r], ep[r], part);
      RED[s * H_ + j] = part;
    }
    __syncthreads();                                            // B1

    // LN(dec) — redundant in ALL waves -> dvA/dvC registers
    float dvA, dvC;
    {
      float a = RED[lane] + RED[128 + lane] + RED[256 + lane] + RED[384 + lane]
              + cap * fcapA + ppA;
      float c = RED[64 + lane] + RED[192 + lane] + RED[320 + lane] + RED[448 + lane]
              + cap * fcapC + ppC;
      float ssum = a + c;
      #pragma unroll
      for (int o = 32; o; o >>= 1) ssum += __shfl_xor(ssum, o, 64);
      const float mu = ssum * (1.f / 128.f);
      const float da = a - mu, dc = c - mu;
      float vvv = da * da + dc * dc;
      #pragma unroll
      for (int o = 32; o; o >>= 1) vvv += __shfl_xor(vvv, o, 64);
      const float inv = 1.0f / sqrtf(vvv * (1.f / 128.f) + EPS_);
      dvA = da * inv * lngA + lnbA;
      dvC = dc * inv * lngC + lnbC;
    }

    // DE (wave = head): q from register-d via bpermute, logits from LDS K, softmax
    {
      const int kbase = (lane >> 4) * 32;
      float q0 = 0.f;
      #pragma unroll
      for (int r = 0; r < 32; ++r) {
        const int idx = (kbase + r) & 63;
        const float tA = __shfl(dvA, idx, 64);
        const float tB = __shfl(dvC, idx, 64);
        q0 = fmaf(wq2[r], (lane < 32) ? tA : tB, q0);
      }
      q0 += __shfl_xor(q0, 16, 64);
      q0 += __shfl_xor(q0, 32, 64);
      float qd[16];
      #pragma unroll
      for (int d = 0; d < 16; ++d) qd[d] = __shfl(q0, d, 64);
      const float* k1 = KH + n1 * SK + wvid * HD_;
      float a1 = 0.f;
      #pragma unroll
      for (int d = 0; d < 16; ++d) a1 = fmaf(qd[d], k1[d], a1);
      a1 = mbA ? NEG_INF : a1 * 0.25f;
      float a2 = NEG_INF;
      if (n2 < N_) {
        const float* k2 = KH + n2 * SK + wvid * HD_;
        float t2 = 0.f;
        #pragma unroll
        for (int d = 0; d < 16; ++d) t2 = fmaf(qd[d], k2[d], t2);
        a2 = mbB ? NEG_INF : t2 * 0.25f;
      }
      float mx = fmaxf(a1, a2);
      #pragma unroll
      for (int o = 32; o; o >>= 1) mx = fmaxf(mx, __shfl_xor(mx, o, 64));
      float e1 = expf(a1 - mx);
      float e2 = (n2 < N_) ? expf(a2 - mx) : 0.f;
      float ssum = e1 + e2;
      #pragma unroll
      for (int o = 32; o; o >>= 1) ssum += __shfl_xor(ssum, o, 64);
      BUF[wvid * N_ + n1] = e1 / ssum;
      if (n2 < N_) BUF[wvid * N_ + n2] = e2 / ssum;
    }
    __syncthreads();                                            // B2

    // F1: x-partials = attn @ V (V in registers)
    {
      const float* aw = BUF + (j >> 4) * N_ + r0;
      float part = 0.f;
      #pragma unroll
      for (int t = 0; t < 26; ++t)
        if (t < nr) part = fmaf(aw[t], vh_r[t], part);
      RED[s * H_ + j] = part;
    }
    __syncthreads();                                            // B3

    // F3: y-partials = x @ wo (x folded inline from RED via float4)
    {
      float y = 0.f;
      #pragma unroll
      for (int r4 = 0; r4 < 8; ++r4) {
        const int k = s * 32 + r4 * 4;
        float4 u0 = *(const float4*)&RED[k];
        float4 u1 = *(const float4*)&RED[128 + k];
        float4 u2 = *(const float4*)&RED[256 + k];
        float4 u3 = *(const float4*)&RED[384 + k];
        y = fmaf(wo_r[r4 * 4 + 0], ((u0.x + u1.x) + u2.x) + u3.x, y);
        y = fmaf(wo_r[r4 * 4 + 1], ((u0.y + u1.y) + u2.y) + u3.y, y);
        y = fmaf(wo_r[r4 * 4 + 2], ((u0.z + u1.z) + u2.z) + u3.z, y);
        y = fmaf(wo_r[r4 * 4 + 3], ((u0.w + u1.w) + u2.w) + u3.w, y);
      }
      BUF[s * H_ + j] = y;
    }
    __syncthreads();                                            // B4

    // LN(ptr) — redundant in ALL waves -> xnA/xnC registers
    float xnA, xnC;
    {
      float a = BUF[lane] + BUF[128 + lane] + BUF[256 + lane] + BUF[384 + lane];
      float c = BUF[64 + lane] + BUF[192 + lane] + BUF[320 + lane] + BUF[448 + lane];
      float ssum = a + c;
      #pragma unroll
      for (int o = 32; o; o >>= 1) ssum += __shfl_xor(ssum, o, 64);
      const float mu = ssum * (1.f / 128.f);
      const float da = a - mu, dc = c - mu;
      float vvv = da * da + dc * dc;
      #pragma unroll
      for (int o = 32; o; o >>= 1) vvv += __shfl_xor(vvv, o, 64);
      const float inv = 1.0f / sqrtf(vvv * (1.f / 128.f) + EPS_);
      xnA = da * inv * plgA + plbA;
      xnC = dc * inv * plgC + plbC;
    }

    // G1: comp halves via register Kp + 64-lane butterflies
    {
      const float dvj = w1 ? xnC : xnA;   // = xn[j]
      #pragma unroll
      for (int t = 0; t < 26; ++t) {
        if (t < nr) {
          float v = dvj * kp_r[t];
          #pragma unroll
          for (int o = 32; o; o >>= 1) v += __shfl_xor(v, o, 64);
          if (lane == 0) CMP[w1 * 256 + r0 + t] = v;
        }
      }
    }
    __syncthreads();                                            // B5

    // G2 — redundant in ALL waves: argmax, lp, state, next masks (registers only)
    {
      const bool allmb = __all(mbA && mbB);
      float c1 = mbA ? NEG_INF : (CMP[n1] + CMP[256 + n1]) * inv_sqrt_h / Tf;
      float c2 = (n2 < N_ && !mbB) ? (CMP[n2] + CMP[256 + n2]) * inv_sqrt_h / Tf : NEG_INF;
      if (allmb) { c1 = 0.f; c2 = (n2 < N_) ? 0.f : NEG_INF; }
      float bv = c1; int bi = n1;
      if (c2 > bv) { bv = c2; bi = n2; }
      #pragma unroll
      for (int o = 32; o; o >>= 1) {
        float ov = __shfl_xor(bv, o, 64);
        int   oi = __shfl_xor(bi, o, 64);
        if (ov > bv || (ov == bv && oi < bi)) { bv = ov; bi = oi; }
      }
      float e1 = expf(c1 - bv);
      float e2 = (n2 < N_) ? expf(c2 - bv) : 0.f;
      float ssum = e1 + e2;
      #pragma unroll
      for (int o = 32; o; o >>= 1) ssum += __shfl_xor(ssum, o, 64);
      float lp = logf((1.0f / ssum + 1e-10f) / PSUM_CONST);
      if (vis >= N_ - 1) lp = 0.f;
      lpsum += lp;
      const float dsel = (bi < 64) ? __shfl(demA, bi, 64) : __shfl(demC, bi - 64, 64);
      cap = (bi == 0) ? capv : (cap - dsel);
      if (bi != 0) {
        const bool newly = ((bi == n1) && !m1a) || ((bi == n2) && !m1c);
        if (__any(newly)) vis += 1;
        m1a = m1a || (bi == n1);
        m1c = m1c || (bi == n2);
      }
      bool infA = (n1 >= 1) && (m1a || demA > cap);
      bool infB = (n2 >= N_) || m1c || (demC > cap);
      bool feasA = (n1 >= 1) && !infA;
      bool feasB = (n2 < N_) && !infB;
      const bool anyf = __any(feasA || feasB);
      const bool depot_m = anyf && (bi == 0);
      mbA = (n1 == 0) ? depot_m : infA;
      mbB = infB;
      pidx = bi;
      if (wvid == 0 && lane == 0) out[(size_t)b * (ns + 2) + 1 + i] = (float)bi;
    }
    // no end-of-loop barrier: next writes (RED in B) are >=2 barriers past their last readers
  }

  if (wvid == 0 && lane == 0) {
    out[(size_t)b * (ns + 2)] = 0.f;
    out[(size_t)b * (ns + 2) + ns + 1] = (pidx == 0) ? -1.f : 0.f;
    out[(size_t)Bv * (ns + 2) + b] = lpsum;   // log_p
  }
}

extern "C" void kernel_launch(void* const* d_in, const int* in_sizes, int n_in,
                              void* d_out, int out_size, void* d_ws, size_t ws_size,
                              hipStream_t stream) {
  const int Bv = in_sizes[0] / (N_ * H_);   // 1024
  const int ns = out_size / Bv - 3;         // B*(ns+2) actions + B log_p => 120
  gat_decoder<<<dim3(Bv), dim3(512), 0, stream>>>(
      (const float*)d_in[0],  (const float*)d_in[1],  (const float*)d_in[2],
      (const float*)d_in[3],  (const float*)d_in[4],  (const float*)d_in[5],
      (const float*)d_in[6],  (const float*)d_in[7],  (const float*)d_in[8],
      (const float*)d_in[9],  (const float*)d_in[10], (const float*)d_in[11],
      (const float*)d_in[12], (const float*)d_in[13], (const float*)d_in[14],
      (const int*)d_in[16],
      (float*)d_out, Bv, ns);
}